// Round 1
// baseline (760.821 us; speedup 1.0000x reference)
//
#include <hip/hip_runtime.h>
#include <hip/hip_bf16.h>
#include <math.h>

// ---------------- constants ----------------
#define BB 8192
#define DD 1024
#define HH 4096
#define EE 4
#define NT 136              // row tiles of 128 covering B*k with per-expert pad to 256
#define CAP (NT * 128)      // 17408 packed-row capacity (256-aligned segments)

typedef __attribute__((ext_vector_type(8))) __bf16 bf16x8;
typedef __attribute__((ext_vector_type(4))) float f32x4;

__device__ __forceinline__ unsigned short f2bf(float f) {
    union { float f; unsigned u; } c; c.f = f;
    unsigned u = c.u;
    unsigned r = (u + 0x7FFFu + ((u >> 16) & 1u)) >> 16;
    return (unsigned short)r;
}

__device__ __forceinline__ void load_lds16(const void* g, void* l) {
    __builtin_amdgcn_global_load_lds(
        (const __attribute__((address_space(1))) void*)g,
        (__attribute__((address_space(3))) void*)l, 16, 0, 0);
}

// raw barrier that (a) does not drain vmcnt, (b) is a compiler memory fence
// on both sides so staged global_load_lds issues cannot be hoisted above it
// nor ds_reads sunk below it.
__device__ __forceinline__ void tile_sync() {
    asm volatile("s_waitcnt vmcnt(0)" ::: "memory");
    __builtin_amdgcn_s_barrier();
    asm volatile("" ::: "memory");
}

// ---------------- weight transpose + bf16 convert ----------------
// src fp32 [E][R][C]  ->  dst bf16 [E][C][R]
template <int R, int C>
__global__ void k_prep(const float* __restrict__ src, unsigned short* __restrict__ dst) {
    __shared__ unsigned short tileT[64 * 72];   // [c][r], pad 72
    const int e = blockIdx.z;
    const int r0 = blockIdx.y * 64, c0 = blockIdx.x * 64;
    const float* s = src + (size_t)e * R * C;
    unsigned short* d = dst + (size_t)e * R * C;
    const int tid = threadIdx.x;
    const int cc = (tid & 15) * 4;
#pragma unroll
    for (int it = 0; it < 4; ++it) {
        int rr = (tid >> 4) + it * 16;
        float4 v = *(const float4*)(s + (size_t)(r0 + rr) * C + c0 + cc);
        tileT[(cc + 0) * 72 + rr] = f2bf(v.x);
        tileT[(cc + 1) * 72 + rr] = f2bf(v.y);
        tileT[(cc + 2) * 72 + rr] = f2bf(v.z);
        tileT[(cc + 3) * 72 + rr] = f2bf(v.w);
    }
    __syncthreads();
#pragma unroll
    for (int it = 0; it < 2; ++it) {
        int chunk = tid + it * 256;
        int cl = chunk >> 3, rl = (chunk & 7) * 8;
        uint4 vv = *(const uint4*)&tileT[cl * 72 + rl];
        *(uint4*)(d + (size_t)(c0 + cl) * R + r0 + rl) = vv;
    }
}

// ---------------- gating: wave-per-row, block-aggregated routing ----------------
__global__ __launch_bounds__(256) void k_gate(
        const float* __restrict__ x, const float* __restrict__ gw,
        const float* __restrict__ gb,
        float* __restrict__ mu, float* __restrict__ rstd,
        int* __restrict__ cnt, int* __restrict__ rows_tmp,
        float* __restrict__ wts_tmp,
        float* __restrict__ probs_out, float* __restrict__ idx_out,
        float* __restrict__ w_out) {
    const int tid = threadIdx.x;
    const int lane = tid & 63, wv = tid >> 6;
    __shared__ int   s_e[64];
    __shared__ float s_w[64];
    __shared__ int   s_pos[64];
    __shared__ int   s_base[4];

    for (int i = 0; i < 8; ++i) {
        const int rloc = wv * 8 + i;
        const int r = blockIdx.x * 32 + rloc;
        float l0 = 0, l1 = 0, l2 = 0, l3 = 0, s = 0, ss = 0;
#pragma unroll
        for (int k = 0; k < 4; ++k) {
            const int off = k * 256 + lane * 4;
            float4 xv = *(const float4*)(x + (size_t)r * DD + off);
            s  += xv.x + xv.y + xv.z + xv.w;
            ss += xv.x * xv.x + xv.y * xv.y + xv.z * xv.z + xv.w * xv.w;
            float4 g0 = *(const float4*)(gw + 0 * DD + off);
            float4 g1 = *(const float4*)(gw + 1 * DD + off);
            float4 g2 = *(const float4*)(gw + 2 * DD + off);
            float4 g3 = *(const float4*)(gw + 3 * DD + off);
            l0 += xv.x * g0.x + xv.y * g0.y + xv.z * g0.z + xv.w * g0.w;
            l1 += xv.x * g1.x + xv.y * g1.y + xv.z * g1.z + xv.w * g1.w;
            l2 += xv.x * g2.x + xv.y * g2.y + xv.z * g2.z + xv.w * g2.w;
            l3 += xv.x * g3.x + xv.y * g3.y + xv.z * g3.z + xv.w * g3.w;
        }
#pragma unroll
        for (int off = 32; off > 0; off >>= 1) {
            l0 += __shfl_xor(l0, off, 64);
            l1 += __shfl_xor(l1, off, 64);
            l2 += __shfl_xor(l2, off, 64);
            l3 += __shfl_xor(l3, off, 64);
            s  += __shfl_xor(s,  off, 64);
            ss += __shfl_xor(ss, off, 64);
        }
        if (lane == 0) {
            float m = s * (1.0f / DD);
            float var = ss * (1.0f / DD) - m * m;
            mu[r] = m;
            rstd[r] = rsqrtf(var + 1e-5f);
            float lg[4] = { l0 + gb[0], l1 + gb[1], l2 + gb[2], l3 + gb[3] };
            float mx = fmaxf(fmaxf(lg[0], lg[1]), fmaxf(lg[2], lg[3]));
            float p[4], tot = 0.f;
#pragma unroll
            for (int e = 0; e < 4; ++e) { p[e] = __expf(lg[e] - mx); tot += p[e]; }
            float inv = 1.0f / tot;
#pragma unroll
            for (int e = 0; e < 4; ++e) { p[e] *= inv; probs_out[(size_t)r * 4 + e] = p[e]; }
            int e0 = 0; float p0 = p[0];
#pragma unroll
            for (int e = 1; e < 4; ++e) if (p[e] > p0) { p0 = p[e]; e0 = e; }
            int e1 = -1; float p1 = -1.f;
#pragma unroll
            for (int e = 0; e < 4; ++e) if (e != e0 && p[e] > p1) { p1 = p[e]; e1 = e; }
            float s2 = 1.0f / (p0 + p1 + 1e-9f);
            float w0 = p0 * s2, w1v = p1 * s2;
            idx_out[r * 2 + 0] = (float)e0;
            idx_out[r * 2 + 1] = (float)e1;
            w_out[r * 2 + 0] = w0;
            w_out[r * 2 + 1] = w1v;
            s_e[rloc * 2 + 0] = e0; s_w[rloc * 2 + 0] = w0;
            s_e[rloc * 2 + 1] = e1; s_w[rloc * 2 + 1] = w1v;
        }
    }
    __syncthreads();
    if (tid < 4) {
        int c = 0;
        for (int k = 0; k < 64; ++k)
            if (s_e[k] == tid) s_pos[k] = c++;
        s_base[tid] = atomicAdd(cnt + tid, c);
    }
    __syncthreads();
    if (tid < 64) {
        int e = s_e[tid];
        int p = s_base[e] + s_pos[tid];
        int r = blockIdx.x * 32 + (tid >> 1);
        rows_tmp[e * BB + p] = r;
        wts_tmp[e * BB + p] = s_w[tid];
    }
}

// ---------------- aux loss + aligned offsets + tile table ----------------
// segments padded to 256 so that 256-row GEMM tiles never straddle experts.
__global__ void k_aux(const float* __restrict__ probs, const int* __restrict__ cnt,
                      int* __restrict__ aoff, int* __restrict__ tile_e,
                      float* __restrict__ aux_out) {
    const int tid = threadIdx.x;
    float s0 = 0, s1 = 0, s2 = 0, s3 = 0;
    for (int r = tid; r < BB; r += 256) {
        float4 p = *(const float4*)(probs + (size_t)r * 4);
        s0 += p.x; s1 += p.y; s2 += p.z; s3 += p.w;
    }
    __shared__ float red[4][256];
    red[0][tid] = s0; red[1][tid] = s1; red[2][tid] = s2; red[3][tid] = s3;
    __syncthreads();
    for (int off = 128; off > 0; off >>= 1) {
        if (tid < off) {
#pragma unroll
            for (int q = 0; q < 4; ++q) red[q][tid] += red[q][tid + off];
        }
        __syncthreads();
    }
    if (tid == 0) {
        float aux = 0.f;
        for (int e = 0; e < 4; ++e) {
            float mean_p = red[e][0] * (1.0f / BB);
            float frac = (float)cnt[e] * (1.0f / (BB * 2));
            aux += frac * mean_p;
        }
        aux_out[0] = 4.0f * aux;
        int a = 0; aoff[0] = 0;
        for (int e = 0; e < 4; ++e) { a += ((cnt[e] + 255) >> 8) << 8; aoff[e + 1] = a; }
        for (int t = 0; t < NT; ++t) {
            int ee = 0;
            for (int e = 0; e < 4; ++e)
                if (t * 128 >= aoff[e] && t * 128 < aoff[e + 1]) ee = e;
            tile_e[t] = ee;
        }
    }
}

// ---------------- pack: gather rows, LN + per-expert affine, bf16 ----------------
__global__ void k_pack(const float* __restrict__ x, const float* __restrict__ lnw,
                       const float* __restrict__ lnb,
                       const float* __restrict__ mu, const float* __restrict__ rstd,
                       const int* __restrict__ cnt, const int* __restrict__ aoff,
                       const int* __restrict__ tile_e,
                       const int* __restrict__ rows_tmp, const float* __restrict__ wts_tmp,
                       int* __restrict__ row_pk, float* __restrict__ wt_pk,
                       unsigned short* __restrict__ Apk) {
    const int i = blockIdx.x;
    if (i >= aoff[4]) return;
    const int e = tile_e[i >> 7];
    const int j = i - aoff[e];
    const int tid = threadIdx.x;
    unsigned short* dst = Apk + (size_t)i * DD + tid * 4;
    if (j < cnt[e]) {
        int b = rows_tmp[e * BB + j];
        if (tid == 0) { row_pk[i] = b; wt_pk[i] = wts_tmp[e * BB + j]; }
        float m = mu[b], rs = rstd[b];
        float4 xv = *(const float4*)(x + (size_t)b * DD + tid * 4);
        float4 wv = *(const float4*)(lnw + (size_t)e * DD + tid * 4);
        float4 bv = *(const float4*)(lnb + (size_t)e * DD + tid * 4);
        ushort4 o;
        o.x = f2bf((xv.x - m) * rs * wv.x + bv.x);
        o.y = f2bf((xv.y - m) * rs * wv.y + bv.y);
        o.z = f2bf((xv.z - m) * rs * wv.z + bv.z);
        o.w = f2bf((xv.w - m) * rs * wv.w + bv.w);
        *(ushort4*)dst = o;
    } else {
        if (tid == 0) { row_pk[i] = -1; wt_pk[i] = 0.f; }
        ushort4 z; z.x = z.y = z.z = z.w = 0;
        *(ushort4*)dst = z;
    }
}

// ---------------- grouped GEMM: 256x256 tile, 8 waves, 4-phase pipelined K-loop ----
// Per-wave 128x64 output (8x4 fragments) -> 1.37x FLOP per LDS byte vs 64x64.
// Double-buffered LDS (128 KiB); per K-tile 4 phases, each:
//   {ds_read quadrant fragments | issue one half-tile global_load_lds into the
//    OTHER buffer}  -> s_barrier -> setprio(1) + 16 MFMA + setprio(0) -> s_barrier
// vmcnt(0) only once per K-tile (loads stay in flight across 1-4 MFMA phases).
// Raster: XCD pair (id&7)>>1 owns a 17-tile row band. KSPLIT==1: xcd&1 picks an
// nb-half. KSPLIT==2: xcd&1 picks the K half (split-K; atomics combine, bias
// added by ks==0 only).
// MODE 1: H = gelu(A @ W^T + b1) -> bf16 Hout
// MODE 2: y[row] += wt * (A @ W^T + b2)
template <int K, int N, int MODE, int KSPLIT>
__global__ __launch_bounds__(512, 2) void moe_gemm(
        const __bf16* __restrict__ A, const __bf16* __restrict__ W,
        const float* __restrict__ bias,
        const int* __restrict__ aoff, const int* __restrict__ tile_e,
        const int* __restrict__ row_pk, const float* __restrict__ wt_pk,
        unsigned short* __restrict__ Hout, float* __restrict__ Y) {
    __shared__ __align__(16) __bf16 As[2][256 * 64];
    __shared__ __align__(16) __bf16 Bs[2][256 * 64];

    constexpr int NBT  = N / 256;
    constexpr int NBX  = (KSPLIT == 1) ? NBT / 2 : NBT;
    constexpr int KSEG = K / KSPLIT;
    constexpr int NKT  = KSEG / 64;

    const int id = blockIdx.x;
    const int xcd = id & 7, slot = id >> 3;
    const int tloc = slot / NBX, nbi = slot % NBX;
    const int t  = (xcd >> 1) * 17 + tloc;
    const int nb = (KSPLIT == 1) ? (xcd & 1) * NBX + nbi : nbi;
    const int ks = (KSPLIT == 1) ? 0 : (xcd & 1);

    if (t * 256 >= aoff[4]) return;
    const int e = tile_e[t * 2];
    const int tid = threadIdx.x;
    const int lane = tid & 63;
    const int wave = tid >> 6;
    const int wm = wave >> 2, wn = wave & 3;     // 2M x 4N wave grid
    const int lm = lane & 15, q = lane >> 4;

    // staging: thread -> row tid>>3 (64 rows/issue), k-chunk slot tid&7,
    // xor-swizzled by row&7 (issue bases are multiples of 64 so swizzle is
    // issue-invariant). LDS dest is linear (wave-uniform base + lane*16B).
    const int srow = tid >> 3;
    const int schunk = ((tid & 7) ^ (srow & 7)) * 8;
    const __bf16* Ag = A + (size_t)(t * 256 + srow) * K + ks * KSEG + schunk;
    const __bf16* Bg = W + (size_t)e * N * K + (size_t)(nb * 256 + srow) * K + ks * KSEG + schunk;

    auto stage = [&](int kt1, int bufi, int m) {   // m: 0=A lo,1=A hi,2=B lo,3=B hi
        const int rb = (m & 1) * 128;
        if (m < 2) {
            load_lds16(Ag + (size_t)rb * K + kt1 * 64,        &As[bufi][rb * 64] + tid * 8);
            load_lds16(Ag + (size_t)(rb + 64) * K + kt1 * 64, &As[bufi][(rb + 64) * 64] + tid * 8);
        } else {
            load_lds16(Bg + (size_t)rb * K + kt1 * 64,        &Bs[bufi][rb * 64] + tid * 8);
            load_lds16(Bg + (size_t)(rb + 64) * K + kt1 * 64, &Bs[bufi][(rb + 64) * 64] + tid * 8);
        }
    };

    f32x4 acc[8][4] = {};

    // prologue: stage K-tile 0 into buf 0
#pragma unroll
    for (int m = 0; m < 4; ++m) stage(0, 0, m);
    tile_sync();

    for (int kt = 0; kt < NKT; ++kt) {
        const int cur = kt & 1, nxt = cur ^ 1;
        const __bf16* Ab = &As[cur][0];
        const __bf16* Bb = &Bs[cur][0];
        const bool pf = (kt + 1 < NKT);

        bf16x8 a0[4][2], b0[2][2];

        // ---- phase 1: read A rows 0..3, B cols 0..1; stage A-lo'; MFMA q(0,0)
#pragma unroll
        for (int i = 0; i < 4; ++i) {
            const int r = wm * 128 + i * 16 + lm;
#pragma unroll
            for (int kk = 0; kk < 2; ++kk)
                a0[i][kk] = *(const bf16x8*)(Ab + r * 64 + (((kk * 4 + q) ^ (r & 7)) * 8));
        }
#pragma unroll
        for (int j = 0; j < 2; ++j) {
            const int r = wn * 64 + j * 16 + lm;
#pragma unroll
            for (int kk = 0; kk < 2; ++kk)
                b0[j][kk] = *(const bf16x8*)(Bb + r * 64 + (((kk * 4 + q) ^ (r & 7)) * 8));
        }
        if (pf) stage(kt + 1, nxt, 0);
        __builtin_amdgcn_s_barrier();
        __builtin_amdgcn_s_setprio(1);
#pragma unroll
        for (int kk = 0; kk < 2; ++kk)
#pragma unroll
            for (int i = 0; i < 4; ++i)
#pragma unroll
                for (int j = 0; j < 2; ++j)
                    acc[i][j] = __builtin_amdgcn_mfma_f32_16x16x32_bf16(a0[i][kk], b0[j][kk], acc[i][j], 0, 0, 0);
        __builtin_amdgcn_s_setprio(0);
        __builtin_amdgcn_s_barrier();

        // ---- phase 2: read B cols 2..3; stage A-hi'; MFMA q(0,1)
#pragma unroll
        for (int j = 0; j < 2; ++j) {
            const int r = wn * 64 + (j + 2) * 16 + lm;
#pragma unroll
            for (int kk = 0; kk < 2; ++kk)
                b0[j][kk] = *(const bf16x8*)(Bb + r * 64 + (((kk * 4 + q) ^ (r & 7)) * 8));
        }
        if (pf) stage(kt + 1, nxt, 1);
        __builtin_amdgcn_s_barrier();
        __builtin_amdgcn_s_setprio(1);
#pragma unroll
        for (int kk = 0; kk < 2; ++kk)
#pragma unroll
            for (int i = 0; i < 4; ++i)
#pragma unroll
                for (int j = 0; j < 2; ++j)
                    acc[i][j + 2] = __builtin_amdgcn_mfma_f32_16x16x32_bf16(a0[i][kk], b0[j][kk], acc[i][j + 2], 0, 0, 0);
        __builtin_amdgcn_s_setprio(0);
        __builtin_amdgcn_s_barrier();

        // ---- phase 3: read A rows 4..7; stage B-lo'; MFMA q(1,1)
#pragma unroll
        for (int i = 0; i < 4; ++i) {
            const int r = wm * 128 + (i + 4) * 16 + lm;
#pragma unroll
            for (int kk = 0; kk < 2; ++kk)
                a0[i][kk] = *(const bf16x8*)(Ab + r * 64 + (((kk * 4 + q) ^ (r & 7)) * 8));
        }
        if (pf) stage(kt + 1, nxt, 2);
        __builtin_amdgcn_s_barrier();
        __builtin_amdgcn_s_setprio(1);
#pragma unroll
        for (int kk = 0; kk < 2; ++kk)
#pragma unroll
            for (int i = 0; i < 4; ++i)
#pragma unroll
                for (int j = 0; j < 2; ++j)
                    acc[i + 4][j + 2] = __builtin_amdgcn_mfma_f32_16x16x32_bf16(a0[i][kk], b0[j][kk], acc[i + 4][j + 2], 0, 0, 0);
        __builtin_amdgcn_s_setprio(0);
        __builtin_amdgcn_s_barrier();

        // ---- phase 4: re-read B cols 0..1; stage B-hi'; MFMA q(1,0); tile sync
#pragma unroll
        for (int j = 0; j < 2; ++j) {
            const int r = wn * 64 + j * 16 + lm;
#pragma unroll
            for (int kk = 0; kk < 2; ++kk)
                b0[j][kk] = *(const bf16x8*)(Bb + r * 64 + (((kk * 4 + q) ^ (r & 7)) * 8));
        }
        if (pf) stage(kt + 1, nxt, 3);
        __builtin_amdgcn_s_barrier();
        __builtin_amdgcn_s_setprio(1);
#pragma unroll
        for (int kk = 0; kk < 2; ++kk)
#pragma unroll
            for (int i = 0; i < 4; ++i)
#pragma unroll
                for (int j = 0; j < 2; ++j)
                    acc[i + 4][j] = __builtin_amdgcn_mfma_f32_16x16x32_bf16(a0[i][kk], b0[j][kk], acc[i + 4][j], 0, 0, 0);
        __builtin_amdgcn_s_setprio(0);
        tile_sync();          // next tile's buffer fully staged; all reads of it long retired
    }

    if (MODE == 1) {
#pragma unroll
        for (int j = 0; j < 4; ++j) {
            const int col = nb * 256 + wn * 64 + j * 16 + lm;
            const float bv = bias[e * N + col];
#pragma unroll
            for (int i = 0; i < 8; ++i) {
                const int rl = wm * 128 + i * 16 + q * 4;
                const size_t base = (size_t)(t * 256 + rl) * N + col;
#pragma unroll
                for (int r = 0; r < 4; ++r) {
                    float v = acc[i][j][r] + bv;
                    float u2 = 2.0f * v * (0.7978845608f + 0.0356774081f * v * v);
                    float g = v / (1.0f + __expf(-u2));
                    Hout[base + (size_t)r * N] = f2bf(g);
                }
            }
        }
    } else {
        float bv[4];
#pragma unroll
        for (int j = 0; j < 4; ++j)
            bv[j] = (ks == 0) ? bias[e * N + nb * 256 + wn * 64 + j * 16 + lm] : 0.f;
#pragma unroll
        for (int i = 0; i < 8; ++i) {
#pragma unroll
            for (int r = 0; r < 4; ++r) {
                const int ig = t * 256 + wm * 128 + i * 16 + q * 4 + r;
                const int brw = row_pk[ig];
                if (brw >= 0) {
                    const float wgt = wt_pk[ig];
#pragma unroll
                    for (int j = 0; j < 4; ++j) {
                        const int col = nb * 256 + wn * 64 + j * 16 + lm;
                        atomicAdd(Y + (size_t)brw * DD + col, (acc[i][j][r] + bv[j]) * wgt);
                    }
                }
            }
        }
    }
}

// ---------------- launch ----------------
extern "C" void kernel_launch(void* const* d_in, const int* in_sizes, int n_in,
                              void* d_out, int out_size, void* d_ws, size_t ws_size,
                              hipStream_t stream) {
    const float* x   = (const float*)d_in[0];
    const float* gw  = (const float*)d_in[1];
    const float* gb  = (const float*)d_in[2];
    const float* lnw = (const float*)d_in[3];
    const float* lnb = (const float*)d_in[4];
    const float* w1  = (const float*)d_in[5];
    const float* b1  = (const float*)d_in[6];
    const float* w2  = (const float*)d_in[7];
    const float* b2  = (const float*)d_in[8];
    float* out = (float*)d_out;

    char* ws = (char*)d_ws;
    size_t o = 0;
    auto alloc = [&](size_t bytes) { size_t r = o; o += (bytes + 255) & ~(size_t)255; return r; };
    float* mu       = (float*)(ws + alloc((size_t)BB * 4));
    float* rstd     = (float*)(ws + alloc((size_t)BB * 4));
    int*   cnt      = (int*)(ws + alloc(16));
    int*   aoff     = (int*)(ws + alloc(5 * 4));
    int*   te       = (int*)(ws + alloc(NT * 4));
    int*   rows_tmp = (int*)(ws + alloc((size_t)EE * BB * 4));
    float* wts_tmp  = (float*)(ws + alloc((size_t)EE * BB * 4));
    int*   row_pk   = (int*)(ws + alloc((size_t)CAP * 4));
    float* wt_pk    = (float*)(ws + alloc((size_t)CAP * 4));
    unsigned short* w1t = (unsigned short*)(ws + alloc((size_t)EE * DD * HH * 2));
    unsigned short* w2t = (unsigned short*)(ws + alloc((size_t)EE * DD * HH * 2));
    unsigned short* Apk = (unsigned short*)(ws + alloc((size_t)CAP * DD * 2));
    unsigned short* Hpk = (unsigned short*)(ws + alloc((size_t)CAP * HH * 2));
    if (o > ws_size) return;  // workspace insufficient: fail loudly

    float* y_out     = out;
    float* probs_out = out + (size_t)BB * DD;
    float* idx_out   = probs_out + (size_t)BB * EE;
    float* w_out     = idx_out + (size_t)BB * 2;
    float* aux_out   = w_out + (size_t)BB * 2;

    hipMemsetAsync(y_out, 0, (size_t)BB * DD * 4, stream);
    hipMemsetAsync(cnt, 0, 16, stream);

    k_prep<DD, HH><<<dim3(HH / 64, DD / 64, EE), 256, 0, stream>>>(w1, w1t);
    k_prep<HH, DD><<<dim3(DD / 64, HH / 64, EE), 256, 0, stream>>>(w2, w2t);
    k_gate<<<BB / 32, 256, 0, stream>>>(x, gw, gb, mu, rstd, cnt, rows_tmp, wts_tmp,
                                        probs_out, idx_out, w_out);
    k_aux<<<1, 256, 0, stream>>>(probs_out, cnt, aoff, te, aux_out);
    k_pack<<<CAP, 256, 0, stream>>>(x, lnw, lnb, mu, rstd, cnt, aoff, te,
                                    rows_tmp, wts_tmp, row_pk, wt_pk, Apk);
    // GEMM1: M=CAP, N=4096, K=1024 -> 68 x 16 tiles = 1088 blocks
    moe_gemm<DD, HH, 1, 1><<<8 * 17 * (HH / 256 / 2), 512, 0, stream>>>(
        (const __bf16*)Apk, (const __bf16*)w1t, b1, aoff, te, nullptr, nullptr, Hpk, nullptr);
    // GEMM2: M=CAP, N=1024, K=4096, split-K=2 -> 68 x 4 x 2 = 544 blocks
    moe_gemm<HH, DD, 2, 2><<<8 * 17 * (DD / 256), 512, 0, stream>>>(
        (const __bf16*)Hpk, (const __bf16*)w2t, b2, aoff, te, row_pk, wt_pk, nullptr, y_out);
}

// Round 2
// 753.882 us; speedup vs baseline: 1.0092x; 1.0092x over previous
//
#include <hip/hip_runtime.h>
#include <hip/hip_bf16.h>
#include <math.h>

// ---------------- constants ----------------
#define BB 8192
#define DD 1024
#define HH 4096
#define EE 4
#define NT 136              // row tiles of 128 covering B*k with per-expert pad to 256
#define CAP (NT * 128)      // 17408 packed-row capacity (256-aligned segments)

typedef __attribute__((ext_vector_type(8))) __bf16 bf16x8;
typedef __attribute__((ext_vector_type(4))) float f32x4;

__device__ __forceinline__ unsigned short f2bf(float f) {
    union { float f; unsigned u; } c; c.f = f;
    unsigned u = c.u;
    unsigned r = (u + 0x7FFFu + ((u >> 16) & 1u)) >> 16;
    return (unsigned short)r;
}

__device__ __forceinline__ void load_lds16(const void* g, void* l) {
    __builtin_amdgcn_global_load_lds(
        (const __attribute__((address_space(1))) void*)g,
        (__attribute__((address_space(3))) void*)l, 16, 0, 0);
}

// ---------------- weight transpose + bf16 convert ----------------
// src fp32 [E][R][C]  ->  dst bf16 [E][C][R]
template <int R, int C>
__global__ void k_prep(const float* __restrict__ src, unsigned short* __restrict__ dst) {
    __shared__ unsigned short tileT[64 * 72];   // [c][r], pad 72
    const int e = blockIdx.z;
    const int r0 = blockIdx.y * 64, c0 = blockIdx.x * 64;
    const float* s = src + (size_t)e * R * C;
    unsigned short* d = dst + (size_t)e * R * C;
    const int tid = threadIdx.x;
    const int cc = (tid & 15) * 4;
#pragma unroll
    for (int it = 0; it < 4; ++it) {
        int rr = (tid >> 4) + it * 16;
        float4 v = *(const float4*)(s + (size_t)(r0 + rr) * C + c0 + cc);
        tileT[(cc + 0) * 72 + rr] = f2bf(v.x);
        tileT[(cc + 1) * 72 + rr] = f2bf(v.y);
        tileT[(cc + 2) * 72 + rr] = f2bf(v.z);
        tileT[(cc + 3) * 72 + rr] = f2bf(v.w);
    }
    __syncthreads();
#pragma unroll
    for (int it = 0; it < 2; ++it) {
        int chunk = tid + it * 256;
        int cl = chunk >> 3, rl = (chunk & 7) * 8;
        uint4 vv = *(const uint4*)&tileT[cl * 72 + rl];
        *(uint4*)(d + (size_t)(c0 + cl) * R + r0 + rl) = vv;
    }
}

// ---------------- gating: wave-per-row, block-aggregated routing ----------------
__global__ __launch_bounds__(256) void k_gate(
        const float* __restrict__ x, const float* __restrict__ gw,
        const float* __restrict__ gb,
        float* __restrict__ mu, float* __restrict__ rstd,
        int* __restrict__ cnt, int* __restrict__ rows_tmp,
        float* __restrict__ wts_tmp,
        float* __restrict__ probs_out, float* __restrict__ idx_out,
        float* __restrict__ w_out) {
    const int tid = threadIdx.x;
    const int lane = tid & 63, wv = tid >> 6;
    __shared__ int   s_e[64];
    __shared__ float s_w[64];
    __shared__ int   s_pos[64];
    __shared__ int   s_base[4];

    for (int i = 0; i < 8; ++i) {
        const int rloc = wv * 8 + i;
        const int r = blockIdx.x * 32 + rloc;
        float l0 = 0, l1 = 0, l2 = 0, l3 = 0, s = 0, ss = 0;
#pragma unroll
        for (int k = 0; k < 4; ++k) {
            const int off = k * 256 + lane * 4;
            float4 xv = *(const float4*)(x + (size_t)r * DD + off);
            s  += xv.x + xv.y + xv.z + xv.w;
            ss += xv.x * xv.x + xv.y * xv.y + xv.z * xv.z + xv.w * xv.w;
            float4 g0 = *(const float4*)(gw + 0 * DD + off);
            float4 g1 = *(const float4*)(gw + 1 * DD + off);
            float4 g2 = *(const float4*)(gw + 2 * DD + off);
            float4 g3 = *(const float4*)(gw + 3 * DD + off);
            l0 += xv.x * g0.x + xv.y * g0.y + xv.z * g0.z + xv.w * g0.w;
            l1 += xv.x * g1.x + xv.y * g1.y + xv.z * g1.z + xv.w * g1.w;
            l2 += xv.x * g2.x + xv.y * g2.y + xv.z * g2.z + xv.w * g2.w;
            l3 += xv.x * g3.x + xv.y * g3.y + xv.z * g3.z + xv.w * g3.w;
        }
#pragma unroll
        for (int off = 32; off > 0; off >>= 1) {
            l0 += __shfl_xor(l0, off, 64);
            l1 += __shfl_xor(l1, off, 64);
            l2 += __shfl_xor(l2, off, 64);
            l3 += __shfl_xor(l3, off, 64);
            s  += __shfl_xor(s,  off, 64);
            ss += __shfl_xor(ss, off, 64);
        }
        if (lane == 0) {
            float m = s * (1.0f / DD);
            float var = ss * (1.0f / DD) - m * m;
            mu[r] = m;
            rstd[r] = rsqrtf(var + 1e-5f);
            float lg[4] = { l0 + gb[0], l1 + gb[1], l2 + gb[2], l3 + gb[3] };
            float mx = fmaxf(fmaxf(lg[0], lg[1]), fmaxf(lg[2], lg[3]));
            float p[4], tot = 0.f;
#pragma unroll
            for (int e = 0; e < 4; ++e) { p[e] = __expf(lg[e] - mx); tot += p[e]; }
            float inv = 1.0f / tot;
#pragma unroll
            for (int e = 0; e < 4; ++e) { p[e] *= inv; probs_out[(size_t)r * 4 + e] = p[e]; }
            int e0 = 0; float p0 = p[0];
#pragma unroll
            for (int e = 1; e < 4; ++e) if (p[e] > p0) { p0 = p[e]; e0 = e; }
            int e1 = -1; float p1 = -1.f;
#pragma unroll
            for (int e = 0; e < 4; ++e) if (e != e0 && p[e] > p1) { p1 = p[e]; e1 = e; }
            float s2 = 1.0f / (p0 + p1 + 1e-9f);
            float w0 = p0 * s2, w1v = p1 * s2;
            idx_out[r * 2 + 0] = (float)e0;
            idx_out[r * 2 + 1] = (float)e1;
            w_out[r * 2 + 0] = w0;
            w_out[r * 2 + 1] = w1v;
            s_e[rloc * 2 + 0] = e0; s_w[rloc * 2 + 0] = w0;
            s_e[rloc * 2 + 1] = e1; s_w[rloc * 2 + 1] = w1v;
        }
    }
    __syncthreads();
    if (tid < 4) {
        int c = 0;
        for (int k = 0; k < 64; ++k)
            if (s_e[k] == tid) s_pos[k] = c++;
        s_base[tid] = atomicAdd(cnt + tid, c);
    }
    __syncthreads();
    if (tid < 64) {
        int e = s_e[tid];
        int p = s_base[e] + s_pos[tid];
        int r = blockIdx.x * 32 + (tid >> 1);
        rows_tmp[e * BB + p] = r;
        wts_tmp[e * BB + p] = s_w[tid];
    }
}

// ---------------- aux loss + aligned offsets + tile table ----------------
// segments padded to 256 so that 256-row GEMM tiles never straddle experts.
__global__ void k_aux(const float* __restrict__ probs, const int* __restrict__ cnt,
                      int* __restrict__ aoff, int* __restrict__ tile_e,
                      float* __restrict__ aux_out) {
    const int tid = threadIdx.x;
    float s0 = 0, s1 = 0, s2 = 0, s3 = 0;
    for (int r = tid; r < BB; r += 256) {
        float4 p = *(const float4*)(probs + (size_t)r * 4);
        s0 += p.x; s1 += p.y; s2 += p.z; s3 += p.w;
    }
    __shared__ float red[4][256];
    red[0][tid] = s0; red[1][tid] = s1; red[2][tid] = s2; red[3][tid] = s3;
    __syncthreads();
    for (int off = 128; off > 0; off >>= 1) {
        if (tid < off) {
#pragma unroll
            for (int q = 0; q < 4; ++q) red[q][tid] += red[q][tid + off];
        }
        __syncthreads();
    }
    if (tid == 0) {
        float aux = 0.f;
        for (int e = 0; e < 4; ++e) {
            float mean_p = red[e][0] * (1.0f / BB);
            float frac = (float)cnt[e] * (1.0f / (BB * 2));
            aux += frac * mean_p;
        }
        aux_out[0] = 4.0f * aux;
        int a = 0; aoff[0] = 0;
        for (int e = 0; e < 4; ++e) { a += ((cnt[e] + 255) >> 8) << 8; aoff[e + 1] = a; }
        for (int t = 0; t < NT; ++t) {
            int ee = 0;
            for (int e = 0; e < 4; ++e)
                if (t * 128 >= aoff[e] && t * 128 < aoff[e + 1]) ee = e;
            tile_e[t] = ee;
        }
    }
}

// ---------------- pack: gather rows, LN + per-expert affine, bf16 ----------------
__global__ void k_pack(const float* __restrict__ x, const float* __restrict__ lnw,
                       const float* __restrict__ lnb,
                       const float* __restrict__ mu, const float* __restrict__ rstd,
                       const int* __restrict__ cnt, const int* __restrict__ aoff,
                       const int* __restrict__ tile_e,
                       const int* __restrict__ rows_tmp, const float* __restrict__ wts_tmp,
                       int* __restrict__ row_pk, float* __restrict__ wt_pk,
                       unsigned short* __restrict__ Apk) {
    const int i = blockIdx.x;
    if (i >= aoff[4]) return;
    const int e = tile_e[i >> 7];
    const int j = i - aoff[e];
    const int tid = threadIdx.x;
    unsigned short* dst = Apk + (size_t)i * DD + tid * 4;
    if (j < cnt[e]) {
        int b = rows_tmp[e * BB + j];
        if (tid == 0) { row_pk[i] = b; wt_pk[i] = wts_tmp[e * BB + j]; }
        float m = mu[b], rs = rstd[b];
        float4 xv = *(const float4*)(x + (size_t)b * DD + tid * 4);
        float4 wv = *(const float4*)(lnw + (size_t)e * DD + tid * 4);
        float4 bv = *(const float4*)(lnb + (size_t)e * DD + tid * 4);
        ushort4 o;
        o.x = f2bf((xv.x - m) * rs * wv.x + bv.x);
        o.y = f2bf((xv.y - m) * rs * wv.y + bv.y);
        o.z = f2bf((xv.z - m) * rs * wv.z + bv.z);
        o.w = f2bf((xv.w - m) * rs * wv.w + bv.w);
        *(ushort4*)dst = o;
    } else {
        if (tid == 0) { row_pk[i] = -1; wt_pk[i] = 0.f; }
        ushort4 z; z.x = z.y = z.z = z.w = 0;
        *(ushort4*)dst = z;
    }
}

// ---------------- grouped GEMM: 256x256 tile, 8 waves, ring-4 BK=32 pipeline ----
// T4 counted-vmcnt structure: 4-deep LDS ring of K=32 tiles (128 KiB), prefetch
// distance 3, ONE barrier per K-tile.  Per tile kt:
//   s_waitcnt vmcnt(8)   // per-wave: tiles kt+1,kt+2 may stay in flight ->
//                        // tile kt's 4 loads (oldest) are retired
//   s_barrier            // collective: buf[kt&3] fully written; also protects
//                        // buf[(kt-1)&3] reads (iter kt-1) from iter-kt stage
//   12x ds_read_b128 (frags) ; stage tile kt+3 -> buf[(kt+3)&3]
//   setprio(1) ; 32x MFMA ; setprio(0)
// vmcnt never drains below 8 in steady state; each load has ~3 tile-times to
// land.  Tail: vmcnt(4) at NKT-2, vmcnt(0) at NKT-1 only.
// Raster: XCD pair (id&7)>>1 owns a 17-tile row band.  KSPLIT==1: xcd&1 picks
// an nb-half.  KSPLIT==2: xcd&1 picks the K half (split-K; atomics combine,
// bias added by ks==0 only).
// MODE 1: H = gelu(A @ W^T + b1) -> bf16 Hout
// MODE 2: y[row] += wt * (A @ W^T + b2)
template <int K, int N, int MODE, int KSPLIT>
__global__ __launch_bounds__(512, 2) void moe_gemm(
        const __bf16* __restrict__ A, const __bf16* __restrict__ W,
        const float* __restrict__ bias,
        const int* __restrict__ aoff, const int* __restrict__ tile_e,
        const int* __restrict__ row_pk, const float* __restrict__ wt_pk,
        unsigned short* __restrict__ Hout, float* __restrict__ Y) {
    __shared__ __align__(16) __bf16 As[4][256 * 32];
    __shared__ __align__(16) __bf16 Bs[4][256 * 32];

    constexpr int NBT  = N / 256;
    constexpr int NBX  = (KSPLIT == 1) ? NBT / 2 : NBT;
    constexpr int KSEG = K / KSPLIT;
    constexpr int NKT  = KSEG / 32;

    const int id = blockIdx.x;
    const int xcd = id & 7, slot = id >> 3;
    const int tloc = slot / NBX, nbi = slot % NBX;
    const int t  = (xcd >> 1) * 17 + tloc;
    const int nb = (KSPLIT == 1) ? (xcd & 1) * NBX + nbi : nbi;
    const int ks = (KSPLIT == 1) ? 0 : (xcd & 1);

    if (t * 256 >= aoff[4]) return;
    const int e = tile_e[t * 2];
    const int tid = threadIdx.x;
    const int lane = tid & 63;
    const int wave = tid >> 6;
    const int wm = wave >> 2, wn = wave & 3;     // 2M x 4N wave grid
    const int lm = lane & 15, q = lane >> 4;

    // staging (BK=32): per K-tile 4 issues (A rows 0-127, A rows 128-255,
    // B rows 0-127, B rows 128-255).  thread -> row tid>>2, 16B chunk tid&3,
    // chunk xor-swizzled by row&3 (row bases are multiples of 128 so the
    // swizzle is issue-invariant).  LDS dest linear: base + tid*16B.
    const int srow = tid >> 2;
    const int schunk = ((tid & 3) ^ (srow & 3)) * 8;
    const __bf16* Ag = A + (size_t)(t * 256 + srow) * K + ks * KSEG + schunk;
    const __bf16* Bg = W + (size_t)e * N * K + (size_t)(nb * 256 + srow) * K + ks * KSEG + schunk;

    f32x4 acc[8][4] = {};

#define STAGE(kt1) do { \
        const int _b = (kt1) & 3; \
        load_lds16(Ag + (size_t)(kt1) * 32,           &As[_b][0]    + tid * 8); \
        load_lds16(Ag + 128 * (size_t)K + (kt1) * 32, &As[_b][4096] + tid * 8); \
        load_lds16(Bg + (size_t)(kt1) * 32,           &Bs[_b][0]    + tid * 8); \
        load_lds16(Bg + 128 * (size_t)K + (kt1) * 32, &Bs[_b][4096] + tid * 8); \
    } while (0)

    STAGE(0); STAGE(1); STAGE(2);

#pragma unroll 1
    for (int kt = 0; kt < NKT; ++kt) {
        const int rem = NKT - 1 - kt;
        if (rem >= 2)      asm volatile("s_waitcnt vmcnt(8)" ::: "memory");
        else if (rem == 1) asm volatile("s_waitcnt vmcnt(4)" ::: "memory");
        else               asm volatile("s_waitcnt vmcnt(0)" ::: "memory");
        __builtin_amdgcn_s_barrier();
        asm volatile("" ::: "memory");

        const __bf16* Ab = &As[kt & 3][0];
        const __bf16* Bb = &Bs[kt & 3][0];
        bf16x8 af[8], bfr[4];
#pragma unroll
        for (int i = 0; i < 8; ++i) {
            const int r = wm * 128 + i * 16 + lm;
            af[i] = *(const bf16x8*)(Ab + r * 32 + ((q ^ (r & 3)) * 8));
        }
#pragma unroll
        for (int j = 0; j < 4; ++j) {
            const int r = wn * 64 + j * 16 + lm;
            bfr[j] = *(const bf16x8*)(Bb + r * 32 + ((q ^ (r & 3)) * 8));
        }
        if (kt + 3 < NKT) STAGE(kt + 3);
        __builtin_amdgcn_s_setprio(1);
#pragma unroll
        for (int i = 0; i < 8; ++i)
#pragma unroll
            for (int j = 0; j < 4; ++j)
                acc[i][j] = __builtin_amdgcn_mfma_f32_16x16x32_bf16(af[i], bfr[j], acc[i][j], 0, 0, 0);
        __builtin_amdgcn_s_setprio(0);
    }
#undef STAGE

    if (MODE == 1) {
#pragma unroll
        for (int j = 0; j < 4; ++j) {
            const int col = nb * 256 + wn * 64 + j * 16 + lm;
            const float bv = bias[e * N + col];
#pragma unroll
            for (int i = 0; i < 8; ++i) {
                const int rl = wm * 128 + i * 16 + q * 4;
                const size_t base = (size_t)(t * 256 + rl) * N + col;
#pragma unroll
                for (int r = 0; r < 4; ++r) {
                    float v = acc[i][j][r] + bv;
                    float u2 = 2.0f * v * (0.7978845608f + 0.0356774081f * v * v);
                    float g = v / (1.0f + __expf(-u2));
                    Hout[base + (size_t)r * N] = f2bf(g);
                }
            }
        }
    } else {
        float bv[4];
#pragma unroll
        for (int j = 0; j < 4; ++j)
            bv[j] = (ks == 0) ? bias[e * N + nb * 256 + wn * 64 + j * 16 + lm] : 0.f;
#pragma unroll
        for (int i = 0; i < 8; ++i) {
#pragma unroll
            for (int r = 0; r < 4; ++r) {
                const int ig = t * 256 + wm * 128 + i * 16 + q * 4 + r;
                const int brw = row_pk[ig];
                if (brw >= 0) {
                    const float wgt = wt_pk[ig];
#pragma unroll
                    for (int j = 0; j < 4; ++j) {
                        const int col = nb * 256 + wn * 64 + j * 16 + lm;
                        atomicAdd(Y + (size_t)brw * DD + col, (acc[i][j][r] + bv[j]) * wgt);
                    }
                }
            }
        }
    }
}

// ---------------- launch ----------------
extern "C" void kernel_launch(void* const* d_in, const int* in_sizes, int n_in,
                              void* d_out, int out_size, void* d_ws, size_t ws_size,
                              hipStream_t stream) {
    const float* x   = (const float*)d_in[0];
    const float* gw  = (const float*)d_in[1];
    const float* gb  = (const float*)d_in[2];
    const float* lnw = (const float*)d_in[3];
    const float* lnb = (const float*)d_in[4];
    const float* w1  = (const float*)d_in[5];
    const float* b1  = (const float*)d_in[6];
    const float* w2  = (const float*)d_in[7];
    const float* b2  = (const float*)d_in[8];
    float* out = (float*)d_out;

    char* ws = (char*)d_ws;
    size_t o = 0;
    auto alloc = [&](size_t bytes) { size_t r = o; o += (bytes + 255) & ~(size_t)255; return r; };
    float* mu       = (float*)(ws + alloc((size_t)BB * 4));
    float* rstd     = (float*)(ws + alloc((size_t)BB * 4));
    int*   cnt      = (int*)(ws + alloc(16));
    int*   aoff     = (int*)(ws + alloc(5 * 4));
    int*   te       = (int*)(ws + alloc(NT * 4));
    int*   rows_tmp = (int*)(ws + alloc((size_t)EE * BB * 4));
    float* wts_tmp  = (float*)(ws + alloc((size_t)EE * BB * 4));
    int*   row_pk   = (int*)(ws + alloc((size_t)CAP * 4));
    float* wt_pk    = (float*)(ws + alloc((size_t)CAP * 4));
    unsigned short* w1t = (unsigned short*)(ws + alloc((size_t)EE * DD * HH * 2));
    unsigned short* w2t = (unsigned short*)(ws + alloc((size_t)EE * DD * HH * 2));
    unsigned short* Apk = (unsigned short*)(ws + alloc((size_t)CAP * DD * 2));
    unsigned short* Hpk = (unsigned short*)(ws + alloc((size_t)CAP * HH * 2));
    if (o > ws_size) return;  // workspace insufficient: fail loudly

    float* y_out     = out;
    float* probs_out = out + (size_t)BB * DD;
    float* idx_out   = probs_out + (size_t)BB * EE;
    float* w_out     = idx_out + (size_t)BB * 2;
    float* aux_out   = w_out + (size_t)BB * 2;

    hipMemsetAsync(y_out, 0, (size_t)BB * DD * 4, stream);
    hipMemsetAsync(cnt, 0, 16, stream);

    k_prep<DD, HH><<<dim3(HH / 64, DD / 64, EE), 256, 0, stream>>>(w1, w1t);
    k_prep<HH, DD><<<dim3(DD / 64, HH / 64, EE), 256, 0, stream>>>(w2, w2t);
    k_gate<<<BB / 32, 256, 0, stream>>>(x, gw, gb, mu, rstd, cnt, rows_tmp, wts_tmp,
                                        probs_out, idx_out, w_out);
    k_aux<<<1, 256, 0, stream>>>(probs_out, cnt, aoff, te, aux_out);
    k_pack<<<CAP, 256, 0, stream>>>(x, lnw, lnb, mu, rstd, cnt, aoff, te,
                                    rows_tmp, wts_tmp, row_pk, wt_pk, Apk);
    // GEMM1: M=CAP, N=4096, K=1024 -> 68 x 16 tiles = 1088 blocks
    moe_gemm<DD, HH, 1, 1><<<8 * 17 * (HH / 256 / 2), 512, 0, stream>>>(
        (const __bf16*)Apk, (const __bf16*)w1t, b1, aoff, te, nullptr, nullptr, Hpk, nullptr);
    // GEMM2: M=CAP, N=1024, K=4096, split-K=2 -> 68 x 4 x 2 = 544 blocks
    moe_gemm<HH, DD, 2, 2><<<8 * 17 * (DD / 256), 512, 0, stream>>>(
        (const __bf16*)Hpk, (const __bf16*)w2t, b2, aoff, te, row_pk, wt_pk, nullptr, y_out);
}

// Round 4
// 650.299 us; speedup vs baseline: 1.1700x; 1.1593x over previous
//
#include <hip/hip_runtime.h>
#include <hip/hip_bf16.h>
#include <math.h>

// ---------------- constants ----------------
#define BB 8192
#define DD 1024
#define HH 4096
#define EE 4
#define NT 132              // row tiles of 128 covering B*k + per-expert pad
#define CAP (NT * 128)      // 16896 packed-row capacity

typedef __attribute__((ext_vector_type(8))) __bf16 bf16x8;
typedef __attribute__((ext_vector_type(4))) float f32x4;

__device__ __forceinline__ unsigned short f2bf(float f) {
    union { float f; unsigned u; } c; c.f = f;
    unsigned u = c.u;
    unsigned r = (u + 0x7FFFu + ((u >> 16) & 1u)) >> 16;
    return (unsigned short)r;
}

__device__ __forceinline__ void load_lds16(const void* g, void* l) {
    __builtin_amdgcn_global_load_lds(
        (const __attribute__((address_space(1))) void*)g,
        (__attribute__((address_space(3))) void*)l, 16, 0, 0);
}

// ---------------- weight transpose + bf16 convert (both weights, one launch) ----
// z<4:  w1 [e][D][H] -> w1t [e][H][D]      (R=D, C=H)
// z>=4: w2 [e][H][D] -> w2t [e][D][H]      (R=H, C=D), grid remapped bijectively
// block (0,0,0) additionally zeroes the control vars for the fused gate/aux.
__global__ void k_prep(const float* __restrict__ w1, const float* __restrict__ w2,
                       unsigned short* __restrict__ w1t, unsigned short* __restrict__ w2t,
                       int* __restrict__ cnt, float* __restrict__ psum,
                       int* __restrict__ done) {
    __shared__ unsigned short tileT[64 * 72];   // [c][r], pad 72
    const int tid = threadIdx.x;
    if (blockIdx.x == 0 && blockIdx.y == 0 && blockIdx.z == 0) {
        if (tid < 4) cnt[tid] = 0;
        else if (tid < 8) psum[tid - 4] = 0.f;
        else if (tid == 8) done[0] = 0;
    }
    const int z = blockIdx.z;
    const float* s;
    unsigned short* d;
    int R, C, r0, c0;
    if (z < 4) {
        s = w1 + (size_t)z * DD * HH;  d = w1t + (size_t)z * DD * HH;
        R = DD; C = HH;
        r0 = blockIdx.y * 64; c0 = blockIdx.x * 64;
    } else {
        const int e = z - 4;
        s = w2 + (size_t)e * DD * HH;  d = w2t + (size_t)e * DD * HH;
        R = HH; C = DD;
        const int idx = blockIdx.y * 64 + blockIdx.x;   // 0..1023
        c0 = (idx & 15) * 64; r0 = (idx >> 4) * 64;
    }
    const int cc = (tid & 15) * 4;
#pragma unroll
    for (int it = 0; it < 4; ++it) {
        int rr = (tid >> 4) + it * 16;
        float4 v = *(const float4*)(s + (size_t)(r0 + rr) * C + c0 + cc);
        tileT[(cc + 0) * 72 + rr] = f2bf(v.x);
        tileT[(cc + 1) * 72 + rr] = f2bf(v.y);
        tileT[(cc + 2) * 72 + rr] = f2bf(v.z);
        tileT[(cc + 3) * 72 + rr] = f2bf(v.w);
    }
    __syncthreads();
#pragma unroll
    for (int it = 0; it < 2; ++it) {
        int chunk = tid + it * 256;
        int cl = chunk >> 3, rl = (chunk & 7) * 8;
        uint4 vv = *(const uint4*)&tileT[cl * 72 + rl];
        *(uint4*)(d + (size_t)(c0 + cl) * R + r0 + rl) = vv;
    }
}

// ---------------- gating + fused aux/offsets: wave-per-row, block routing ------
// Each block: 32 rows.  Block-local prob sums -> global atomic psum; routing
// counts -> atomic cnt.  The LAST block (ticket) computes aux loss, 128-aligned
// segment offsets, and the tile->expert table (work previously in k_aux).
__global__ __launch_bounds__(256) void k_gate(
        const float* __restrict__ x, const float* __restrict__ gw,
        const float* __restrict__ gb,
        float* __restrict__ mu, float* __restrict__ rstd,
        int* __restrict__ cnt, float* __restrict__ psum, int* __restrict__ done,
        int* __restrict__ rows_tmp, float* __restrict__ wts_tmp,
        float* __restrict__ probs_out, float* __restrict__ idx_out,
        float* __restrict__ w_out,
        int* __restrict__ aoff, int* __restrict__ tile_e,
        float* __restrict__ aux_out) {
    const int tid = threadIdx.x;
    const int lane = tid & 63, wv = tid >> 6;
    __shared__ int   s_e[64];
    __shared__ float s_w[64];
    __shared__ int   s_pos[64];
    __shared__ int   s_base[4];
    __shared__ float s_ps[4][4];    // [wave][expert]
    __shared__ int   s_last;

    float lp0 = 0.f, lp1 = 0.f, lp2 = 0.f, lp3 = 0.f;   // lane0-only prob sums

    for (int i = 0; i < 8; ++i) {
        const int rloc = wv * 8 + i;
        const int r = blockIdx.x * 32 + rloc;
        float l0 = 0, l1 = 0, l2 = 0, l3 = 0, s = 0, ss = 0;
#pragma unroll
        for (int k = 0; k < 4; ++k) {
            const int off = k * 256 + lane * 4;
            float4 xv = *(const float4*)(x + (size_t)r * DD + off);
            s  += xv.x + xv.y + xv.z + xv.w;
            ss += xv.x * xv.x + xv.y * xv.y + xv.z * xv.z + xv.w * xv.w;
            float4 g0 = *(const float4*)(gw + 0 * DD + off);
            float4 g1 = *(const float4*)(gw + 1 * DD + off);
            float4 g2 = *(const float4*)(gw + 2 * DD + off);
            float4 g3 = *(const float4*)(gw + 3 * DD + off);
            l0 += xv.x * g0.x + xv.y * g0.y + xv.z * g0.z + xv.w * g0.w;
            l1 += xv.x * g1.x + xv.y * g1.y + xv.z * g1.z + xv.w * g1.w;
            l2 += xv.x * g2.x + xv.y * g2.y + xv.z * g2.z + xv.w * g2.w;
            l3 += xv.x * g3.x + xv.y * g3.y + xv.z * g3.z + xv.w * g3.w;
        }
#pragma unroll
        for (int off = 32; off > 0; off >>= 1) {
            l0 += __shfl_xor(l0, off, 64);
            l1 += __shfl_xor(l1, off, 64);
            l2 += __shfl_xor(l2, off, 64);
            l3 += __shfl_xor(l3, off, 64);
            s  += __shfl_xor(s,  off, 64);
            ss += __shfl_xor(ss, off, 64);
        }
        if (lane == 0) {
            float m = s * (1.0f / DD);
            float var = ss * (1.0f / DD) - m * m;
            mu[r] = m;
            rstd[r] = rsqrtf(var + 1e-5f);
            float lg[4] = { l0 + gb[0], l1 + gb[1], l2 + gb[2], l3 + gb[3] };
            float mx = fmaxf(fmaxf(lg[0], lg[1]), fmaxf(lg[2], lg[3]));
            float p[4], tot = 0.f;
#pragma unroll
            for (int e = 0; e < 4; ++e) { p[e] = __expf(lg[e] - mx); tot += p[e]; }
            float inv = 1.0f / tot;
#pragma unroll
            for (int e = 0; e < 4; ++e) { p[e] *= inv; probs_out[(size_t)r * 4 + e] = p[e]; }
            lp0 += p[0]; lp1 += p[1]; lp2 += p[2]; lp3 += p[3];
            int e0 = 0; float p0 = p[0];
#pragma unroll
            for (int e = 1; e < 4; ++e) if (p[e] > p0) { p0 = p[e]; e0 = e; }
            int e1 = -1; float p1 = -1.f;
#pragma unroll
            for (int e = 0; e < 4; ++e) if (e != e0 && p[e] > p1) { p1 = p[e]; e1 = e; }
            float s2 = 1.0f / (p0 + p1 + 1e-9f);
            float w0 = p0 * s2, w1v = p1 * s2;
            idx_out[r * 2 + 0] = (float)e0;
            idx_out[r * 2 + 1] = (float)e1;
            w_out[r * 2 + 0] = w0;
            w_out[r * 2 + 1] = w1v;
            s_e[rloc * 2 + 0] = e0; s_w[rloc * 2 + 0] = w0;
            s_e[rloc * 2 + 1] = e1; s_w[rloc * 2 + 1] = w1v;
        }
    }
    if (lane == 0) {
        s_ps[wv][0] = lp0; s_ps[wv][1] = lp1; s_ps[wv][2] = lp2; s_ps[wv][3] = lp3;
    }
    __syncthreads();
    if (tid < 4) {                      // block-local count + position assign
        int c = 0;
        for (int k = 0; k < 64; ++k)
            if (s_e[k] == tid) s_pos[k] = c++;
        s_base[tid] = atomicAdd(cnt + tid, c);
        atomicAdd(psum + tid, s_ps[0][tid] + s_ps[1][tid] + s_ps[2][tid] + s_ps[3][tid]);
    }
    __syncthreads();
    if (tid < 64) {
        int e = s_e[tid];
        int p = s_base[e] + s_pos[tid];
        int r = blockIdx.x * 32 + (tid >> 1);
        rows_tmp[e * BB + p] = r;
        wts_tmp[e * BB + p] = s_w[tid];
    }
    // ---- fused aux tail: last block computes aux loss, aoff, tile table ----
    __threadfence();
    __syncthreads();
    if (tid == 0) s_last = atomicAdd(done, 1);
    __syncthreads();
    if (s_last == (int)gridDim.x - 1 && tid == 0) {
        int c[4];
        for (int e = 0; e < 4; ++e) c[e] = atomicAdd(cnt + e, 0);       // coherent read
        float aux = 0.f;
        int a = 0; aoff[0] = 0;
        for (int e = 0; e < 4; ++e) {
            float mean_p = atomicAdd(psum + e, 0.f) * (1.0f / BB);
            aux += ((float)c[e] * (1.0f / (BB * 2))) * mean_p;
            a += ((c[e] + 127) >> 7) << 7; aoff[e + 1] = a;
        }
        aux_out[0] = 4.0f * aux;
        for (int t = 0; t < NT; ++t) {
            int ee = 0;
            for (int e = 0; e < 4; ++e)
                if (t * 128 >= aoff[e] && t * 128 < aoff[e + 1]) ee = e;
            tile_e[t] = ee;
        }
    }
}

// ---------------- pack: gather rows, LN + affine, bf16; also zeroes y ----------
// 4 packed rows per block (wave-per-row); blocks < BB/4 additionally zero 4 rows
// of the output accumulator y (replaces the 32 MB hipMemsetAsync).
__global__ __launch_bounds__(256) void k_pack(
        const float* __restrict__ x, const float* __restrict__ lnw,
        const float* __restrict__ lnb,
        const float* __restrict__ mu, const float* __restrict__ rstd,
        const int* __restrict__ cnt, const int* __restrict__ aoff,
        const int* __restrict__ tile_e,
        const int* __restrict__ rows_tmp, const float* __restrict__ wts_tmp,
        int* __restrict__ row_pk, float* __restrict__ wt_pk,
        unsigned short* __restrict__ Apk, float* __restrict__ y) {
    const int blk = blockIdx.x, tid = threadIdx.x;
    const int wv = tid >> 6, lane = tid & 63;
    if (blk < BB / 4) {
        float4 z4; z4.x = z4.y = z4.z = z4.w = 0.f;
        float* yr = y + (size_t)(blk * 4 + wv) * DD + lane * 4;
#pragma unroll
        for (int k = 0; k < 4; ++k) *(float4*)(yr + k * 256) = z4;
    }
    const int i = blk * 4 + wv;
    if (i >= aoff[4]) return;
    const int e = tile_e[i >> 7];
    const int j = i - aoff[e];
    unsigned short* dst = Apk + (size_t)i * DD;
    if (j < cnt[e]) {
        int b = rows_tmp[e * BB + j];
        if (lane == 0) { row_pk[i] = b; wt_pk[i] = wts_tmp[e * BB + j]; }
        float m = mu[b], rs = rstd[b];
#pragma unroll
        for (int k = 0; k < 4; ++k) {
            const int off = k * 256 + lane * 4;
            float4 xv = *(const float4*)(x + (size_t)b * DD + off);
            float4 wv4 = *(const float4*)(lnw + (size_t)e * DD + off);
            float4 bv4 = *(const float4*)(lnb + (size_t)e * DD + off);
            ushort4 o;
            o.x = f2bf((xv.x - m) * rs * wv4.x + bv4.x);
            o.y = f2bf((xv.y - m) * rs * wv4.y + bv4.y);
            o.z = f2bf((xv.z - m) * rs * wv4.z + bv4.z);
            o.w = f2bf((xv.w - m) * rs * wv4.w + bv4.w);
            *(ushort4*)(dst + off) = o;
        }
    } else {
        if (lane == 0) { row_pk[i] = -1; wt_pk[i] = 0.f; }
        ushort4 z; z.x = z.y = z.z = z.w = 0;
#pragma unroll
        for (int k = 0; k < 4; ++k) *(ushort4*)(dst + k * 256 + lane * 4) = z;
    }
}

// ---------------- grouped GEMM (m97 recipe, BK=64, XCD-aware raster) ----------
// 1-D grid. xcd = id&7 (HW round-robin); XCD pair (xcd>>1) owns a contiguous
// band of 33 row-tiles; xcd&1 picks an nb-half. Slot order: nbg -> tloc -> nbi
// so B groups stay L2-resident while the A band streams once per group.
// MODE 1: H = gelu(A @ W^T + b1) -> bf16 Hout     (K=1024, N=4096)
// MODE 2: y[row] += wt * (A @ W^T + b2)           (K=4096, N=1024)
template <int K, int N, int MODE>
__global__ void moe_gemm(const __bf16* __restrict__ A, const __bf16* __restrict__ W,
                         const float* __restrict__ bias,
                         const int* __restrict__ aoff, const int* __restrict__ tile_e,
                         const int* __restrict__ row_pk, const float* __restrict__ wt_pk,
                         unsigned short* __restrict__ Hout, float* __restrict__ Y) {
    __shared__ __align__(16) __bf16 As[128 * 64];
    __shared__ __align__(16) __bf16 Bs[128 * 64];

    constexpr int NBHALF = N / 128 / 2;                 // nb per XCD half
    constexpr int NBGRP  = (NBHALF >= 8) ? 8 : NBHALF;  // L2-resident B group
    const int id = blockIdx.x;
    const int xcd = id & 7, slot = id >> 3;
    const int nbg  = slot / (33 * NBGRP);
    const int rem  = slot - nbg * (33 * NBGRP);
    const int tloc = rem / NBGRP;
    const int nbi  = rem - tloc * NBGRP;
    const int t  = (xcd >> 1) * 33 + tloc;
    const int nb = (xcd & 1) * NBHALF + nbg * NBGRP + nbi;

    if (t * 128 >= aoff[4]) return;
    const int e = tile_e[t];
    const int tid = threadIdx.x;
    const int lane = tid & 63;
    const int wave = tid >> 6;
    const int wm = wave & 1, wn = wave >> 1;
    const int lm = lane & 15, q = lane >> 4;

    // staging (BK=64): 4 issues each for A and B; issue i covers rows
    // [i*32, i*32+32), thread -> row i*32+(tid>>3), k-chunk slot tid&7,
    // xor-swizzled by row&7 ((i*32)&7 == 0 so swizzle is issue-invariant).
    const int srow = tid >> 3;
    const int schunk = ((tid & 7) ^ (srow & 7)) * 8;
    const __bf16* Ag = A + (size_t)(t * 128 + srow) * K + schunk;
    const __bf16* Bg = W + (size_t)e * N * K + (size_t)(nb * 128 + srow) * K + schunk;
    __bf16* Al = As + tid * 8;
    __bf16* Bl = Bs + tid * 8;

    f32x4 acc[4][4] = {};
    int arow[4], brow[4];
#pragma unroll
    for (int i = 0; i < 4; ++i) {
        arow[i] = wm * 64 + i * 16 + lm;
        brow[i] = wn * 64 + i * 16 + lm;
    }

    for (int kt = 0; kt < K / 64; ++kt) {
#pragma unroll
        for (int i = 0; i < 4; ++i) load_lds16(Ag + (size_t)i * 32 * K + kt * 64, Al + i * 2048);
#pragma unroll
        for (int i = 0; i < 4; ++i) load_lds16(Bg + (size_t)i * 32 * K + kt * 64, Bl + i * 2048);
        __syncthreads();
#pragma unroll
        for (int kk = 0; kk < 2; ++kk) {
            bf16x8 af[4], bfr[4];
#pragma unroll
            for (int i = 0; i < 4; ++i)
                af[i] = *(const bf16x8*)(As + arow[i] * 64 + (((kk * 4 + q) ^ (arow[i] & 7)) * 8));
#pragma unroll
            for (int j = 0; j < 4; ++j)
                bfr[j] = *(const bf16x8*)(Bs + brow[j] * 64 + (((kk * 4 + q) ^ (brow[j] & 7)) * 8));
#pragma unroll
            for (int i = 0; i < 4; ++i)
#pragma unroll
                for (int j = 0; j < 4; ++j)
                    acc[i][j] = __builtin_amdgcn_mfma_f32_16x16x32_bf16(af[i], bfr[j], acc[i][j], 0, 0, 0);
        }
        __syncthreads();
    }

    if (MODE == 1) {
#pragma unroll
        for (int j = 0; j < 4; ++j) {
            int col = nb * 128 + wn * 64 + j * 16 + lm;
            float bv = bias[e * N + col];
#pragma unroll
            for (int i = 0; i < 4; ++i) {
                int rl = wm * 64 + i * 16 + q * 4;
                size_t base = (size_t)(t * 128 + rl) * N + col;
#pragma unroll
                for (int r = 0; r < 4; ++r) {
                    float v = acc[i][j][r] + bv;
                    // tanh-form GELU via sigmoid: v * sigmoid(2u)
                    float u2 = 2.0f * v * (0.7978845608f + 0.0356774081f * v * v);
                    float g = v / (1.0f + __expf(-u2));
                    Hout[base + (size_t)r * N] = f2bf(g);
                }
            }
        }
    } else {
        float bv[4];
#pragma unroll
        for (int j = 0; j < 4; ++j) bv[j] = bias[e * N + nb * 128 + wn * 64 + j * 16 + lm];
#pragma unroll
        for (int i = 0; i < 4; ++i) {
#pragma unroll
            for (int r = 0; r < 4; ++r) {
                int ig = t * 128 + wm * 64 + i * 16 + q * 4 + r;
                int brw = row_pk[ig];
                if (brw >= 0) {
                    float wgt = wt_pk[ig];
#pragma unroll
                    for (int j = 0; j < 4; ++j) {
                        int col = nb * 128 + wn * 64 + j * 16 + lm;
                        atomicAdd(Y + (size_t)brw * DD + col, (acc[i][j][r] + bv[j]) * wgt);
                    }
                }
            }
        }
    }
}

// ---------------- launch ----------------
extern "C" void kernel_launch(void* const* d_in, const int* in_sizes, int n_in,
                              void* d_out, int out_size, void* d_ws, size_t ws_size,
                              hipStream_t stream) {
    const float* x   = (const float*)d_in[0];
    const float* gw  = (const float*)d_in[1];
    const float* gb  = (const float*)d_in[2];
    const float* lnw = (const float*)d_in[3];
    const float* lnb = (const float*)d_in[4];
    const float* w1  = (const float*)d_in[5];
    const float* b1  = (const float*)d_in[6];
    const float* w2  = (const float*)d_in[7];
    const float* b2  = (const float*)d_in[8];
    float* out = (float*)d_out;

    char* ws = (char*)d_ws;
    size_t o = 0;
    auto alloc = [&](size_t bytes) { size_t r = o; o += (bytes + 255) & ~(size_t)255; return r; };
    float* mu       = (float*)(ws + alloc((size_t)BB * 4));
    float* rstd     = (float*)(ws + alloc((size_t)BB * 4));
    int*   cnt      = (int*)(ws + alloc(16));
    float* psum     = (float*)(ws + alloc(16));
    int*   done     = (int*)(ws + alloc(16));
    int*   aoff     = (int*)(ws + alloc(5 * 4));
    int*   te       = (int*)(ws + alloc(NT * 4));
    int*   rows_tmp = (int*)(ws + alloc((size_t)EE * BB * 4));
    float* wts_tmp  = (float*)(ws + alloc((size_t)EE * BB * 4));
    int*   row_pk   = (int*)(ws + alloc((size_t)CAP * 4));
    float* wt_pk    = (float*)(ws + alloc((size_t)CAP * 4));
    unsigned short* w1t = (unsigned short*)(ws + alloc((size_t)EE * DD * HH * 2));
    unsigned short* w2t = (unsigned short*)(ws + alloc((size_t)EE * DD * HH * 2));
    unsigned short* Apk = (unsigned short*)(ws + alloc((size_t)CAP * DD * 2));
    unsigned short* Hpk = (unsigned short*)(ws + alloc((size_t)CAP * HH * 2));
    if (o > ws_size) return;  // workspace insufficient: fail loudly

    float* y_out     = out;
    float* probs_out = out + (size_t)BB * DD;
    float* idx_out   = probs_out + (size_t)BB * EE;
    float* w_out     = idx_out + (size_t)BB * 2;
    float* aux_out   = w_out + (size_t)BB * 2;

    // 5 dispatches total; no memsets (cnt/psum/done zeroed in k_prep, y in k_pack)
    k_prep<<<dim3(64, 16, 8), 256, 0, stream>>>(w1, w2, w1t, w2t, cnt, psum, done);
    k_gate<<<BB / 32, 256, 0, stream>>>(x, gw, gb, mu, rstd, cnt, psum, done,
                                        rows_tmp, wts_tmp, probs_out, idx_out, w_out,
                                        aoff, te, aux_out);
    k_pack<<<CAP / 4, 256, 0, stream>>>(x, lnw, lnb, mu, rstd, cnt, aoff, te,
                                        rows_tmp, wts_tmp, row_pk, wt_pk, Apk, y_out);
    moe_gemm<DD, HH, 1><<<8 * 33 * (HH / 256), 256, 0, stream>>>(
        (const __bf16*)Apk, (const __bf16*)w1t, b1, aoff, te, nullptr, nullptr, Hpk, nullptr);
    moe_gemm<HH, DD, 2><<<8 * 33 * (DD / 256), 256, 0, stream>>>(
        (const __bf16*)Hpk, (const __bf16*)w2t, b2, aoff, te, row_pk, wt_pk, nullptr, y_out);
}